// Round 4
// baseline (1175.264 us; speedup 1.0000x reference)
//
#include <hip/hip_runtime.h>

// LinearAttention: B=16, T=4096, D=512, LR=0.01
//   q,k,v = x @ W^T ; S += LR * sum_b v k^T (before readout) ; out = S q
// Chunked: chunk = 64 time steps = 1024 rows (time-major r = t*16 + b).
// Causality is at time-step granularity = 16 rows = one MFMA tile.
//
// MFMA convention (gfx950 16x16x32 bf16):
//   D[m][n] = sum_k A[m][k] B[k][n]
//   A-frag: lane holds A[m=lane&15][k=(lane>>4)*8 + j]  (8 consecutive k)
//   B-frag: lane holds B[k=(lane>>4)*8+j][n=lane&15]    (8 consecutive k, fixed n)
//   C/D   : D[row=(lane>>4)*4+i][col=lane&15]
// Storage: qb,kb: [r][e] (e contig)   kt: [c][e][rl]   vt: [c][d][rl]
//
// R6 (out_kernel was 1 block/CU by GRID SIZE -> concurrency-starved):
//  * out_kernel: 512 blocks, ONE 128-row tile per block. c = bx&63 (XCD pin);
//    rt mapped so bx and bx+256 carry complementary tiles {7-g, g} -> CUs
//    receive balanced pairs. 2 blocks/CU = 16 waves/CU (was 8).
//  * state_kernel: 1D grid, c = bx&63 -> a chunk's 16 blocks stay on one XCD
//    (was consecutive ids sprayed across all 8 XCDs).
// proj (R5), cvt, scan unchanged.

#define LR_ 0.01f

typedef __attribute__((ext_vector_type(8))) short   short8v;   // bf16x8 frag
typedef __attribute__((ext_vector_type(4))) float   f32x4;     // acc
typedef __attribute__((ext_vector_type(4))) unsigned short us4;
typedef __attribute__((ext_vector_type(8))) unsigned short us8;

__device__ __forceinline__ unsigned short f2bf(float f) {
    unsigned int u = __float_as_uint(f);
    return (unsigned short)((u + 0x7FFFu + ((u >> 16) & 1u)) >> 16); // RNE
}

// ---------------------------------------------------------------- K0: fp32->bf16
__global__ __launch_bounds__(256) void cvt_kernel(const float* __restrict__ s,
                                                  unsigned short* __restrict__ d, int n) {
    int i = (blockIdx.x * 256 + threadIdx.x) * 8;
    if (i + 8 <= n) {
        f32x4 a = *(const f32x4*)(s + i);
        f32x4 b = *(const f32x4*)(s + i + 4);
        us8 o;
        #pragma unroll
        for (int j = 0; j < 4; j++) { o[j] = f2bf(a[j]); o[j + 4] = f2bf(b[j]); }
        *(us8*)(d + i) = o;
    } else {
        for (; i < n; i++) d[i] = f2bf(s[i]);
    }
}

// ---------------------------------------------------------------- K1: projections
// R5: block = 64 rows x 512 cols x 3 mats. x tile in LDS (staged once, padded),
// W streamed from L2. 4 waves; wave wc owns cols wc*128..+128 (acc[4][8]).
__global__ __launch_bounds__(256, 2) void proj_kernel(
    const unsigned short* __restrict__ xb, const unsigned short* __restrict__ wb,
    unsigned short* __restrict__ qb, unsigned short* __restrict__ kb,
    unsigned short* __restrict__ kt, unsigned short* __restrict__ vt) {
    __shared__ unsigned short Xs[64][520];     // 64 rows x 512 (+8 pad) = 65 KB

    const int rowTile = blockIdx.x;            // 0..1023
    const int tid = threadIdx.x, wid = tid >> 6, lane = tid & 63;
    const int quad = lane >> 4, l16 = lane & 15;
    const int wc = wid;                        // wave col 0..3
    const int r0 = rowTile * 64;

    // ---- stage x tile: each wave loads one full row (1 KB) per pass, coalesced
    {
        const int m = (tid >> 6);              // base row for this wave's pass
        #pragma unroll
        for (int p = 0; p < 16; ++p) {
            const int row = p * 4 + m;         // 0..63
            const int r = r0 + row;
            const int i = ((r & 15) << 12) | (r >> 4);   // x row = b*4096 + t
            us8 v = *(const us8*)(xb + i * 512 + lane * 8);
            *(us8*)&Xs[row][lane * 8] = v;
        }
    }
    __syncthreads();

    #pragma unroll
    for (int mat = 0; mat < 3; ++mat) {
        const unsigned short* wmat = wb + mat * (512 * 512);
        const unsigned short* brow[8];
        #pragma unroll
        for (int nt = 0; nt < 8; ++nt)
            brow[nt] = wmat + (wc * 128 + nt * 16 + l16) * 512 + quad * 8;

        f32x4 acc[4][8];
        #pragma unroll
        for (int a = 0; a < 4; ++a)
            #pragma unroll
            for (int b = 0; b < 8; ++b) acc[a][b] = (f32x4)0.f;

        #pragma unroll 2
        for (int k0 = 0; k0 < 512; k0 += 32) {
            short8v aq[4], bs[8];
            #pragma unroll
            for (int nt = 0; nt < 8; ++nt) bs[nt] = *(const short8v*)(brow[nt] + k0);
            #pragma unroll
            for (int mt = 0; mt < 4; ++mt)
                aq[mt] = *(const short8v*)&Xs[mt * 16 + l16][k0 + quad * 8];
            #pragma unroll
            for (int mt = 0; mt < 4; ++mt)
                #pragma unroll
                for (int nt = 0; nt < 8; ++nt)
                    acc[mt][nt] = __builtin_amdgcn_mfma_f32_16x16x32_bf16(
                        aq[mt], bs[nt], acc[mt][nt], 0, 0, 0);
        }

        // ---- epilogue for this mat
        #pragma unroll
        for (int mt = 0; mt < 4; ++mt) {
            const int rbase = r0 + mt * 16 + quad * 4;   // 4 consecutive rows
            const int c = rbase >> 10, rl = rbase & 1023;
            #pragma unroll
            for (int nt = 0; nt < 8; ++nt) {
                const int e = wc * 128 + nt * 16 + l16;
                unsigned short h[4];
                #pragma unroll
                for (int i = 0; i < 4; i++) h[i] = f2bf(acc[mt][nt][i]);
                if (mat == 0) {
                    #pragma unroll
                    for (int i = 0; i < 4; i++) qb[(rbase + i) * 512 + e] = h[i];
                } else if (mat == 1) {
                    #pragma unroll
                    for (int i = 0; i < 4; i++) kb[(rbase + i) * 512 + e] = h[i];
                    us4 p; p[0] = h[0]; p[1] = h[1]; p[2] = h[2]; p[3] = h[3];
                    *(us4*)(kt + (c * 512 + e) * 1024 + rl) = p;
                } else {
                    us4 p; p[0] = h[0]; p[1] = h[1]; p[2] = h[2]; p[3] = h[3];
                    *(us4*)(vt + (c * 512 + e) * 1024 + rl) = p;
                }
            }
        }
    }
}

// ---------------------------------------------------------------- K2: per-chunk G = sum_r v (x) k
// R6: 1D grid, c = bx&63 -> chunk's 16 blocks share an XCD (L2 locality).
__global__ __launch_bounds__(256) void state_kernel(
    const unsigned short* __restrict__ kt, const unsigned short* __restrict__ vt,
    float* __restrict__ G) {
    const int bx = blockIdx.x;
    const int c = bx & 63;
    const int tileId = bx >> 6;               // 0..15
    const int dTile = tileId >> 2, eTile = tileId & 3;
    const int tid = threadIdx.x, wid = tid >> 6, lane = tid & 63;
    const int quad = lane >> 4, l16 = lane & 15;
    const int d0 = dTile * 128 + (wid >> 1) * 64;
    const int e0 = eTile * 128 + (wid & 1) * 64;

    f32x4 acc[4][4];
    #pragma unroll
    for (int a = 0; a < 4; a++)
        #pragma unroll
        for (int b = 0; b < 4; b++) acc[a][b] = (f32x4)0.f;

    const unsigned short* ar[4];
    const unsigned short* br[4];
    #pragma unroll
    for (int mt = 0; mt < 4; mt++) ar[mt] = vt + (c * 512 + d0 + mt * 16 + l16) * 1024 + quad * 8;
    #pragma unroll
    for (int nt = 0; nt < 4; nt++) br[nt] = kt + (c * 512 + e0 + nt * 16 + l16) * 1024 + quad * 8;

    short8v a[2][4], b[2][4];
    #pragma unroll
    for (int mt = 0; mt < 4; mt++) a[0][mt] = *(const short8v*)(ar[mt]);
    #pragma unroll
    for (int nt = 0; nt < 4; nt++) b[0][nt] = *(const short8v*)(br[nt]);

    #pragma unroll 2
    for (int rl = 0; rl < 1024; rl += 32) {
        const int cur = (rl >> 5) & 1, nxt = cur ^ 1;
        if (rl < 992) {
            #pragma unroll
            for (int mt = 0; mt < 4; mt++) a[nxt][mt] = *(const short8v*)(ar[mt] + rl + 32);
            #pragma unroll
            for (int nt = 0; nt < 4; nt++) b[nxt][nt] = *(const short8v*)(br[nt] + rl + 32);
        }
        #pragma unroll
        for (int mt = 0; mt < 4; mt++)
            #pragma unroll
            for (int nt = 0; nt < 4; nt++)
                acc[mt][nt] = __builtin_amdgcn_mfma_f32_16x16x32_bf16(
                    a[cur][mt], b[cur][nt], acc[mt][nt], 0, 0, 0);
    }

    float* g = G + (size_t)c * 262144;
    #pragma unroll
    for (int mt = 0; mt < 4; mt++)
        #pragma unroll
        for (int nt = 0; nt < 4; nt++)
            #pragma unroll
            for (int i = 0; i < 4; i++)
                g[(d0 + mt * 16 + quad * 4 + i) * 512 + (e0 + nt * 16 + l16)] = acc[mt][nt][i];
}

// ---------------------------------------------------------------- K3: exclusive prefix over chunks
__global__ __launch_bounds__(256) void scan_kernel(const float* __restrict__ G,
                                                   const float* __restrict__ m0,
                                                   unsigned short* __restrict__ Sp) {
    int idx = blockIdx.x * 256 + threadIdx.x;   // (d,e) flat, 262144 total
    float s = m0[idx];
    for (int c = 0; c < 64; c++) {
        Sp[c * 262144 + idx] = f2bf(s);
        s += LR_ * G[c * 262144 + idx];
    }
}

// ---------------------------------------------------------------- K4: fused out = Q@Sp^T + intra
// R6: 512 blocks x 512 threads (8 waves, 2 blocks/CU). Block = (chunk c =
// bx&63, ONE row-tile rt). rt map: bx<256 -> 7-g, bx>=256 -> g (g=(bx>>6)&3)
// so bx and bx+256 are complementary {big, small} -> balanced CU pairs.
// Wave (wr=wid>>2, wc=wid&3) owns 64 rows x 128 cols: acc[4][8] f32x4.
// inter GEMM (K=512, Sp b-frags direct), then j = 0..rt K-tiles of 128 rows:
// scores (each wave a 64x32 P sub-tile) -> LDS panel (XOR-swizzled, double-
// buffered, 1 barrier/j) -> PV (panel a-frags, vt b-frags direct). Diagonal
// j==rt masked at 16x16 sub-tile granularity.
__global__ __launch_bounds__(512, 2) void out_kernel(
    const unsigned short* __restrict__ qb, const unsigned short* __restrict__ kb,
    const unsigned short* __restrict__ vt, const unsigned short* __restrict__ Sp,
    float* __restrict__ out) {
    __shared__ unsigned short Ps[2][16384];   // [buf][128 rows][16 slots of 8] 64 KB

    const int bx  = blockIdx.x;
    const int c   = bx & 63;                  // chunk; c%8 = bx%8 -> XCD-pinned
    const int g   = (bx >> 6) & 3;
    const int rt  = (bx >> 8) ? g : 7 - g;    // row-tile 0..7, complementary pairs
    const int tid = threadIdx.x, wid = tid >> 6, lane = tid & 63;
    const int quad = lane >> 4, l16 = lane & 15;
    const int wr = wid >> 2, wc = wid & 3;    // wave row 0..1, wave col 0..3

    const unsigned short* qbc = qb + (size_t)c * 524288;
    const unsigned short* kbc = kb + (size_t)c * 524288;
    const unsigned short* vtc = vt + (size_t)c * 524288;
    const unsigned short* spc = Sp + (size_t)c * 262144;

    const unsigned short* sprow[8];
    #pragma unroll
    for (int nt = 0; nt < 8; ++nt)
        sprow[nt] = spc + (wc * 128 + nt * 16 + l16) * 512 + quad * 8;

    const int r0 = rt * 128 + wr * 64;        // wave's first chunk-local row

    const unsigned short* qrow[4];
    #pragma unroll
    for (int mt = 0; mt < 4; ++mt)
        qrow[mt] = qbc + (r0 + mt * 16 + l16) * 512 + quad * 8;

    f32x4 acc[4][8];
    #pragma unroll
    for (int a = 0; a < 4; ++a)
        #pragma unroll
        for (int b = 0; b < 8; ++b) acc[a][b] = (f32x4)0.f;

    // ---- inter: acc += Q @ Sp^T
    #pragma unroll 2
    for (int k0 = 0; k0 < 512; k0 += 32) {
        short8v aq[4], bs[8];
        #pragma unroll
        for (int mt = 0; mt < 4; ++mt) aq[mt] = *(const short8v*)(qrow[mt] + k0);
        #pragma unroll
        for (int nt = 0; nt < 8; ++nt) bs[nt] = *(const short8v*)(sprow[nt] + k0);
        #pragma unroll
        for (int mt = 0; mt < 4; ++mt)
            #pragma unroll
            for (int nt = 0; nt < 8; ++nt)
                acc[mt][nt] = __builtin_amdgcn_mfma_f32_16x16x32_bf16(
                    aq[mt], bs[nt], acc[mt][nt], 0, 0, 0);
    }

    // ---- intra: j-tiles of 128 k-rows
    for (int j = 0; j <= rt; ++j) {
        // scores: this wave's 64x32 P sub-tile (rows r0.., cols wc*32..)
        f32x4 sc[4][2];
        #pragma unroll
        for (int a = 0; a < 4; ++a) { sc[a][0] = (f32x4)0.f; sc[a][1] = (f32x4)0.f; }
        const unsigned short* krow0 = kbc + (j * 128 + wc * 32 + l16) * 512 + quad * 8;
        const unsigned short* krow1 = krow0 + 16 * 512;
        #pragma unroll 2
        for (int k0 = 0; k0 < 512; k0 += 32) {
            short8v b0 = *(const short8v*)(krow0 + k0);
            short8v b1 = *(const short8v*)(krow1 + k0);
            #pragma unroll
            for (int mt = 0; mt < 4; ++mt) {
                short8v aq = *(const short8v*)(qrow[mt] + k0);
                sc[mt][0] = __builtin_amdgcn_mfma_f32_16x16x32_bf16(aq, b0, sc[mt][0], 0, 0, 0);
                sc[mt][1] = __builtin_amdgcn_mfma_f32_16x16x32_bf16(aq, b1, sc[mt][1], 0, 0, 0);
            }
        }
        if (j == rt) {   // diagonal: zero sub-tiles with kstep > tstep
            #pragma unroll
            for (int mt = 0; mt < 4; ++mt)
                #pragma unroll
                for (int nt = 0; nt < 2; ++nt)
                    if (wc * 2 + nt > wr * 4 + mt) sc[mt][nt] = (f32x4)0.f;
        }
        // panel write (D-frag -> A-frag relayout, slot ^= row&15)
        const int pb = j & 1;
        unsigned short* pw = &Ps[pb][0];
        #pragma unroll
        for (int mt = 0; mt < 4; ++mt) {
            const int mrow = wr * 64 + mt * 16 + quad * 4;
            #pragma unroll
            for (int nt = 0; nt < 2; ++nt) {
                const int n = wc * 32 + nt * 16 + l16;
                #pragma unroll
                for (int i = 0; i < 4; ++i) {
                    const int m = mrow + i;
                    pw[m * 128 + ((((n >> 3) ^ (m & 15)) << 3) | (n & 7))] =
                        f2bf(sc[mt][nt][i] * LR_);
                }
            }
        }
        __syncthreads();
        // PV: acc += P @ V  (panel a-frags; vt b-frags direct, k=rl contig)
        #pragma unroll
        for (int kt = 0; kt < 4; ++kt) {
            short8v pa[4];
            #pragma unroll
            for (int mt = 0; mt < 4; ++mt) {
                const int m = wr * 64 + mt * 16 + l16;     // m&15 == l16
                pa[mt] = *(const short8v*)&Ps[pb][m * 128 + (((kt * 4 + quad) ^ l16) << 3)];
            }
            const unsigned short* vkk = vtc + j * 128 + kt * 32 + quad * 8;
            #pragma unroll
            for (int nt = 0; nt < 8; ++nt) {
                short8v bv = *(const short8v*)(vkk + (wc * 128 + nt * 16 + l16) * 1024);
                #pragma unroll
                for (int mt = 0; mt < 4; ++mt)
                    acc[mt][nt] = __builtin_amdgcn_mfma_f32_16x16x32_bf16(
                        pa[mt], bv, acc[mt][nt], 0, 0, 0);
            }
        }
        // no trailing barrier: next j writes the other panel buffer; the
        // per-j barrier above orders write(pb^1) after all reads(pb^1).
    }

    // ---- epilogue: out[b][t][d], b = quad*4+i, t = c*64+rt*8+wr*4+mt
    #pragma unroll
    for (int mt = 0; mt < 4; ++mt) {
        const int tglob = c * 64 + rt * 8 + wr * 4 + mt;
        #pragma unroll
        for (int i = 0; i < 4; ++i) {
            float* orow = out + (size_t)(quad * 4 + i) * 2097152
                              + (size_t)tglob * 512 + wc * 128 + l16;
            #pragma unroll
            for (int nt = 0; nt < 8; ++nt)
                orow[nt * 16] = acc[mt][nt][i];
        }
    }
}

// ---------------------------------------------------------------- launch
extern "C" void kernel_launch(void* const* d_in, const int* in_sizes, int n_in,
                              void* d_out, int out_size, void* d_ws, size_t ws_size,
                              hipStream_t stream) {
    (void)in_sizes; (void)n_in; (void)out_size; (void)ws_size;
    const float* x  = (const float*)d_in[0];
    const float* Wq = (const float*)d_in[1];
    const float* Wk = (const float*)d_in[2];
    const float* Wv = (const float*)d_in[3];
    const float* m0 = (const float*)d_in[4];

    char* w = (char*)d_ws;
    unsigned short* xb = (unsigned short*)(w + 0);            //  64 MB
    unsigned short* wb = (unsigned short*)(w + 67108864);     // 1.5 MB
    unsigned short* qb = (unsigned short*)(w + 68681728);     //  64 MB  [r][e]
    unsigned short* kb = (unsigned short*)(w + 135790592);    //  64 MB  [r][e]
    unsigned short* kt = (unsigned short*)(w + 202899456);    //  64 MB  [c][e][rl]
    unsigned short* vt = (unsigned short*)(w + 270008320);    //  64 MB  [c][d][rl]
    float*          G  = (float*)(w + 337117184);             //  64 MB  [c][d][e]
    unsigned short* Sp = (unsigned short*)(w + 404226048);    //  32 MB  [c][d][e]

    cvt_kernel<<<16384, 256, 0, stream>>>(x, xb, 33554432);
    cvt_kernel<<<128, 256, 0, stream>>>(Wq, wb, 262144);
    cvt_kernel<<<128, 256, 0, stream>>>(Wk, wb + 262144, 262144);
    cvt_kernel<<<128, 256, 0, stream>>>(Wv, wb + 524288, 262144);

    proj_kernel<<<1024, 256, 0, stream>>>(xb, wb, qb, kb, kt, vt);
    state_kernel<<<1024, 256, 0, stream>>>(kt, vt, G);
    scan_kernel<<<1024, 256, 0, stream>>>(G, m0, Sp);
    out_kernel<<<512, 512, 0, stream>>>(qb, kb, vt, Sp, (float*)d_out);
}

// Round 5
// 928.295 us; speedup vs baseline: 1.2660x; 1.2660x over previous
//
#include <hip/hip_runtime.h>

// LinearAttention: B=16, T=4096, D=512, LR=0.01
//   q,k,v = x @ W^T ; S += LR * sum_b v k^T (before readout) ; out = S q
// Chunked: chunk = 64 time steps = 1024 rows (time-major r = t*16 + b).
// Causality is at time-step granularity = 16 rows = one MFMA tile.
//
// MFMA convention (gfx950 16x16x32 bf16):
//   D[m][n] = sum_k A[m][k] B[k][n]
//   A-frag: lane holds A[m=lane&15][k=(lane>>4)*8 + j]  (8 consecutive k)
//   B-frag: lane holds B[k=(lane>>4)*8+j][n=lane&15]    (8 consecutive k, fixed n)
//   C/D   : D[row=(lane>>4)*4+i][col=lane&15]
// Storage: qb,kb: [r][e] (e contig)   kt: [c][e][rl]   vt: [c][d][rl]
//
// R7 (R6's one-tile-per-block regressed: early-finish tail; R5's FETCH
// breakdown shows Q re-reads = ~360 MB of the 609 MB = the excess):
//  * out_kernel: back to R5's balanced 256 blocks x {pr,7-pr} pairs (11
//    equal units per block), PLUS Q staged in LDS once per half (128 KB,
//    XOR-swizzled slot^=row&15, no pad) -> Q read from HBM once, score
//    and inter A-frags become ds_read_b128.
//  * P panel single-buffered (32 KB; LDS total = exactly 160 KB), so
//    2 barriers per j-tile.
//  * state_kernel keeps R6's XCD-pinned 1D grid.

#define LR_ 0.01f

typedef __attribute__((ext_vector_type(8))) short   short8v;   // bf16x8 frag
typedef __attribute__((ext_vector_type(4))) float   f32x4;     // acc
typedef __attribute__((ext_vector_type(4))) unsigned short us4;
typedef __attribute__((ext_vector_type(8))) unsigned short us8;

__device__ __forceinline__ unsigned short f2bf(float f) {
    unsigned int u = __float_as_uint(f);
    return (unsigned short)((u + 0x7FFFu + ((u >> 16) & 1u)) >> 16); // RNE
}

// ---------------------------------------------------------------- K0: fp32->bf16
__global__ __launch_bounds__(256) void cvt_kernel(const float* __restrict__ s,
                                                  unsigned short* __restrict__ d, int n) {
    int i = (blockIdx.x * 256 + threadIdx.x) * 8;
    if (i + 8 <= n) {
        f32x4 a = *(const f32x4*)(s + i);
        f32x4 b = *(const f32x4*)(s + i + 4);
        us8 o;
        #pragma unroll
        for (int j = 0; j < 4; j++) { o[j] = f2bf(a[j]); o[j + 4] = f2bf(b[j]); }
        *(us8*)(d + i) = o;
    } else {
        for (; i < n; i++) d[i] = f2bf(s[i]);
    }
}

// ---------------------------------------------------------------- K1: projections
// R5: block = 64 rows x 512 cols x 3 mats. x tile in LDS (staged once, padded),
// W streamed from L2. 4 waves; wave wc owns cols wc*128..+128 (acc[4][8]).
__global__ __launch_bounds__(256, 2) void proj_kernel(
    const unsigned short* __restrict__ xb, const unsigned short* __restrict__ wb,
    unsigned short* __restrict__ qb, unsigned short* __restrict__ kb,
    unsigned short* __restrict__ kt, unsigned short* __restrict__ vt) {
    __shared__ unsigned short Xs[64][520];     // 64 rows x 512 (+8 pad) = 65 KB

    const int rowTile = blockIdx.x;            // 0..1023
    const int tid = threadIdx.x, wid = tid >> 6, lane = tid & 63;
    const int quad = lane >> 4, l16 = lane & 15;
    const int wc = wid;                        // wave col 0..3
    const int r0 = rowTile * 64;

    // ---- stage x tile: each wave loads one full row (1 KB) per pass, coalesced
    {
        const int m = (tid >> 6);              // base row for this wave's pass
        #pragma unroll
        for (int p = 0; p < 16; ++p) {
            const int row = p * 4 + m;         // 0..63
            const int r = r0 + row;
            const int i = ((r & 15) << 12) | (r >> 4);   // x row = b*4096 + t
            us8 v = *(const us8*)(xb + i * 512 + lane * 8);
            *(us8*)&Xs[row][lane * 8] = v;
        }
    }
    __syncthreads();

    #pragma unroll
    for (int mat = 0; mat < 3; ++mat) {
        const unsigned short* wmat = wb + mat * (512 * 512);
        const unsigned short* brow[8];
        #pragma unroll
        for (int nt = 0; nt < 8; ++nt)
            brow[nt] = wmat + (wc * 128 + nt * 16 + l16) * 512 + quad * 8;

        f32x4 acc[4][8];
        #pragma unroll
        for (int a = 0; a < 4; ++a)
            #pragma unroll
            for (int b = 0; b < 8; ++b) acc[a][b] = (f32x4)0.f;

        #pragma unroll 2
        for (int k0 = 0; k0 < 512; k0 += 32) {
            short8v aq[4], bs[8];
            #pragma unroll
            for (int nt = 0; nt < 8; ++nt) bs[nt] = *(const short8v*)(brow[nt] + k0);
            #pragma unroll
            for (int mt = 0; mt < 4; ++mt)
                aq[mt] = *(const short8v*)&Xs[mt * 16 + l16][k0 + quad * 8];
            #pragma unroll
            for (int mt = 0; mt < 4; ++mt)
                #pragma unroll
                for (int nt = 0; nt < 8; ++nt)
                    acc[mt][nt] = __builtin_amdgcn_mfma_f32_16x16x32_bf16(
                        aq[mt], bs[nt], acc[mt][nt], 0, 0, 0);
        }

        // ---- epilogue for this mat
        #pragma unroll
        for (int mt = 0; mt < 4; ++mt) {
            const int rbase = r0 + mt * 16 + quad * 4;   // 4 consecutive rows
            const int c = rbase >> 10, rl = rbase & 1023;
            #pragma unroll
            for (int nt = 0; nt < 8; ++nt) {
                const int e = wc * 128 + nt * 16 + l16;
                unsigned short h[4];
                #pragma unroll
                for (int i = 0; i < 4; i++) h[i] = f2bf(acc[mt][nt][i]);
                if (mat == 0) {
                    #pragma unroll
                    for (int i = 0; i < 4; i++) qb[(rbase + i) * 512 + e] = h[i];
                } else if (mat == 1) {
                    #pragma unroll
                    for (int i = 0; i < 4; i++) kb[(rbase + i) * 512 + e] = h[i];
                    us4 p; p[0] = h[0]; p[1] = h[1]; p[2] = h[2]; p[3] = h[3];
                    *(us4*)(kt + (c * 512 + e) * 1024 + rl) = p;
                } else {
                    us4 p; p[0] = h[0]; p[1] = h[1]; p[2] = h[2]; p[3] = h[3];
                    *(us4*)(vt + (c * 512 + e) * 1024 + rl) = p;
                }
            }
        }
    }
}

// ---------------------------------------------------------------- K2: per-chunk G = sum_r v (x) k
// R6: 1D grid, c = bx&63 -> chunk's 16 blocks share an XCD (L2 locality).
__global__ __launch_bounds__(256) void state_kernel(
    const unsigned short* __restrict__ kt, const unsigned short* __restrict__ vt,
    float* __restrict__ G) {
    const int bx = blockIdx.x;
    const int c = bx & 63;
    const int tileId = bx >> 6;               // 0..15
    const int dTile = tileId >> 2, eTile = tileId & 3;
    const int tid = threadIdx.x, wid = tid >> 6, lane = tid & 63;
    const int quad = lane >> 4, l16 = lane & 15;
    const int d0 = dTile * 128 + (wid >> 1) * 64;
    const int e0 = eTile * 128 + (wid & 1) * 64;

    f32x4 acc[4][4];
    #pragma unroll
    for (int a = 0; a < 4; a++)
        #pragma unroll
        for (int b = 0; b < 4; b++) acc[a][b] = (f32x4)0.f;

    const unsigned short* ar[4];
    const unsigned short* br[4];
    #pragma unroll
    for (int mt = 0; mt < 4; mt++) ar[mt] = vt + (c * 512 + d0 + mt * 16 + l16) * 1024 + quad * 8;
    #pragma unroll
    for (int nt = 0; nt < 4; nt++) br[nt] = kt + (c * 512 + e0 + nt * 16 + l16) * 1024 + quad * 8;

    short8v a[2][4], b[2][4];
    #pragma unroll
    for (int mt = 0; mt < 4; mt++) a[0][mt] = *(const short8v*)(ar[mt]);
    #pragma unroll
    for (int nt = 0; nt < 4; nt++) b[0][nt] = *(const short8v*)(br[nt]);

    #pragma unroll 2
    for (int rl = 0; rl < 1024; rl += 32) {
        const int cur = (rl >> 5) & 1, nxt = cur ^ 1;
        if (rl < 992) {
            #pragma unroll
            for (int mt = 0; mt < 4; mt++) a[nxt][mt] = *(const short8v*)(ar[mt] + rl + 32);
            #pragma unroll
            for (int nt = 0; nt < 4; nt++) b[nxt][nt] = *(const short8v*)(br[nt] + rl + 32);
        }
        #pragma unroll
        for (int mt = 0; mt < 4; mt++)
            #pragma unroll
            for (int nt = 0; nt < 4; nt++)
                acc[mt][nt] = __builtin_amdgcn_mfma_f32_16x16x32_bf16(
                    a[cur][mt], b[cur][nt], acc[mt][nt], 0, 0, 0);
    }

    float* g = G + (size_t)c * 262144;
    #pragma unroll
    for (int mt = 0; mt < 4; mt++)
        #pragma unroll
        for (int nt = 0; nt < 4; nt++)
            #pragma unroll
            for (int i = 0; i < 4; i++)
                g[(d0 + mt * 16 + quad * 4 + i) * 512 + (e0 + nt * 16 + l16)] = acc[mt][nt][i];
}

// ---------------------------------------------------------------- K3: exclusive prefix over chunks
__global__ __launch_bounds__(256) void scan_kernel(const float* __restrict__ G,
                                                   const float* __restrict__ m0,
                                                   unsigned short* __restrict__ Sp) {
    int idx = blockIdx.x * 256 + threadIdx.x;   // (d,e) flat, 262144 total
    float s = m0[idx];
    for (int c = 0; c < 64; c++) {
        Sp[c * 262144 + idx] = f2bf(s);
        s += LR_ * G[c * 262144 + idx];
    }
}

// ---------------------------------------------------------------- K4: fused out = Q@Sp^T + intra
// R7: 256 blocks x 512 threads. Block = (chunk c = bx&63, pair {pr,7-pr}):
// 11 equal work units per block (balanced). Per half (128 rows):
//  * Q staged to LDS Qs once (128x512 bf16, XOR slot^=row&15, no pad) ->
//    score/inter A-frags are ds_read_b128; Q hits HBM once per half.
//  * inter GEMM (Sp b-frags direct from L2), then j=0..rt tiles: scores
//    (K b-frags direct) -> single-buffered P panel (32 KB, swizzled) ->
//    PV (vt b-frags direct). 2 barriers per j. Diagonal masked per 16x16.
__global__ __launch_bounds__(512, 2) void out_kernel(
    const unsigned short* __restrict__ qb, const unsigned short* __restrict__ kb,
    const unsigned short* __restrict__ vt, const unsigned short* __restrict__ Sp,
    float* __restrict__ out) {
    __shared__ unsigned short Qs[128 * 512];   // 128 KB, swizzled
    __shared__ unsigned short Ps[128 * 128];   // 32 KB, swizzled

    const int bx  = blockIdx.x;
    const int c   = bx & 63;                  // chunk; c%8 = bx%8 -> XCD-pinned
    const int pr  = bx >> 6;                  // pair id 0..3
    const int tid = threadIdx.x, wid = tid >> 6, lane = tid & 63;
    const int quad = lane >> 4, l16 = lane & 15;
    const int wr = wid >> 2, wc = wid & 3;    // wave row 0..1, wave col 0..3

    const unsigned short* qbc = qb + (size_t)c * 524288;
    const unsigned short* kbc = kb + (size_t)c * 524288;
    const unsigned short* vtc = vt + (size_t)c * 524288;
    const unsigned short* spc = Sp + (size_t)c * 262144;

    const unsigned short* sprow[8];
    #pragma unroll
    for (int nt = 0; nt < 8; ++nt)
        sprow[nt] = spc + (wc * 128 + nt * 16 + l16) * 512 + quad * 8;

    for (int half = 0; half < 2; ++half) {
        const int rt = half ? (7 - pr) : pr;      // row-tile 0..7
        const int rowbase = wr * 64;              // wave's half-local first row

        __syncthreads();                          // Qs/Ps reuse guard
        // ---- stage Q half-tile: wave wid stages rows wid*16..+15 (coalesced 1KB)
        {
            const unsigned short* qsrc = qbc + (size_t)(rt * 128 + wid * 16) * 512;
            #pragma unroll
            for (int p = 0; p < 16; ++p) {
                const int row = wid * 16 + p;     // 0..127, row&15 == p
                us8 v = *(const us8*)(qsrc + p * 512 + lane * 8);
                *(us8*)&Qs[row * 512 + ((lane ^ p) << 3)] = v;
            }
        }
        __syncthreads();

        f32x4 acc[4][8];
        #pragma unroll
        for (int a = 0; a < 4; ++a)
            #pragma unroll
            for (int b = 0; b < 8; ++b) acc[a][b] = (f32x4)0.f;

        // ---- inter: acc += Q @ Sp^T   (A from LDS, B from L2)
        #pragma unroll 2
        for (int k0 = 0; k0 < 512; k0 += 32) {
            short8v aq[4], bs[8];
            #pragma unroll
            for (int nt = 0; nt < 8; ++nt) bs[nt] = *(const short8v*)(sprow[nt] + k0);
            #pragma unroll
            for (int mt = 0; mt < 4; ++mt) {
                const int row = rowbase + mt * 16 + l16;   // row&15 == l16
                aq[mt] = *(const short8v*)&Qs[row * 512 + ((((k0 >> 3) + quad) ^ l16) << 3)];
            }
            #pragma unroll
            for (int mt = 0; mt < 4; ++mt)
                #pragma unroll
                for (int nt = 0; nt < 8; ++nt)
                    acc[mt][nt] = __builtin_amdgcn_mfma_f32_16x16x32_bf16(
                        aq[mt], bs[nt], acc[mt][nt], 0, 0, 0);
        }

        // ---- intra: j-tiles of 128 k-rows
        for (int j = 0; j <= rt; ++j) {
            // scores: this wave's 64x32 P sub-tile (rows rowbase.., cols wc*32..)
            f32x4 sc[4][2];
            #pragma unroll
            for (int a = 0; a < 4; ++a) { sc[a][0] = (f32x4)0.f; sc[a][1] = (f32x4)0.f; }
            const unsigned short* krow0 = kbc + (j * 128 + wc * 32 + l16) * 512 + quad * 8;
            const unsigned short* krow1 = krow0 + 16 * 512;
            #pragma unroll 2
            for (int k0 = 0; k0 < 512; k0 += 32) {
                short8v b0 = *(const short8v*)(krow0 + k0);
                short8v b1 = *(const short8v*)(krow1 + k0);
                #pragma unroll
                for (int mt = 0; mt < 4; ++mt) {
                    const int row = rowbase + mt * 16 + l16;
                    short8v aq = *(const short8v*)&Qs[row * 512 + ((((k0 >> 3) + quad) ^ l16) << 3)];
                    sc[mt][0] = __builtin_amdgcn_mfma_f32_16x16x32_bf16(aq, b0, sc[mt][0], 0, 0, 0);
                    sc[mt][1] = __builtin_amdgcn_mfma_f32_16x16x32_bf16(aq, b1, sc[mt][1], 0, 0, 0);
                }
            }
            if (j == rt) {   // diagonal: zero sub-tiles with kstep > tstep
                #pragma unroll
                for (int mt = 0; mt < 4; ++mt)
                    #pragma unroll
                    for (int nt = 0; nt < 2; ++nt)
                        if (wc * 2 + nt > wr * 4 + mt) sc[mt][nt] = (f32x4)0.f;
            }
            // panel write (D-frag -> A-frag relayout, slot ^= row&15)
            #pragma unroll
            for (int mt = 0; mt < 4; ++mt) {
                const int mrow = wr * 64 + mt * 16 + quad * 4;
                #pragma unroll
                for (int nt = 0; nt < 2; ++nt) {
                    const int n = wc * 32 + nt * 16 + l16;
                    #pragma unroll
                    for (int i = 0; i < 4; ++i) {
                        const int m = mrow + i;
                        Ps[m * 128 + ((((n >> 3) ^ (m & 15)) << 3) | (n & 7))] =
                            f2bf(sc[mt][nt][i] * LR_);
                    }
                }
            }
            __syncthreads();
            // PV: acc += P @ V  (panel a-frags; vt b-frags direct, k=rl contig)
            #pragma unroll
            for (int kt = 0; kt < 4; ++kt) {
                short8v pa[4];
                #pragma unroll
                for (int mt = 0; mt < 4; ++mt) {
                    const int m = wr * 64 + mt * 16 + l16;     // m&15 == l16
                    pa[mt] = *(const short8v*)&Ps[m * 128 + (((kt * 4 + quad) ^ l16) << 3)];
                }
                const unsigned short* vkk = vtc + j * 128 + kt * 32 + quad * 8;
                #pragma unroll
                for (int nt = 0; nt < 8; ++nt) {
                    short8v bv = *(const short8v*)(vkk + (wc * 128 + nt * 16 + l16) * 1024);
                    #pragma unroll
                    for (int mt = 0; mt < 4; ++mt)
                        acc[mt][nt] = __builtin_amdgcn_mfma_f32_16x16x32_bf16(
                            pa[mt], bv, acc[mt][nt], 0, 0, 0);
                }
            }
            __syncthreads();   // single panel buffer: next j's writes wait
        }

        // ---- epilogue: out[b][t][d], b = quad*4+i, t = c*64+rt*8+wr*4+mt
        #pragma unroll
        for (int mt = 0; mt < 4; ++mt) {
            const int tglob = c * 64 + rt * 8 + wr * 4 + mt;
            #pragma unroll
            for (int i = 0; i < 4; ++i) {
                float* orow = out + (size_t)(quad * 4 + i) * 2097152
                                  + (size_t)tglob * 512 + wc * 128 + l16;
                #pragma unroll
                for (int nt = 0; nt < 8; ++nt)
                    orow[nt * 16] = acc[mt][nt][i];
            }
        }
    }
}

// ---------------------------------------------------------------- launch
extern "C" void kernel_launch(void* const* d_in, const int* in_sizes, int n_in,
                              void* d_out, int out_size, void* d_ws, size_t ws_size,
                              hipStream_t stream) {
    (void)in_sizes; (void)n_in; (void)out_size; (void)ws_size;
    const float* x  = (const float*)d_in[0];
    const float* Wq = (const float*)d_in[1];
    const float* Wk = (const float*)d_in[2];
    const float* Wv = (const float*)d_in[3];
    const float* m0 = (const float*)d_in[4];

    char* w = (char*)d_ws;
    unsigned short* xb = (unsigned short*)(w + 0);            //  64 MB
    unsigned short* wb = (unsigned short*)(w + 67108864);     // 1.5 MB
    unsigned short* qb = (unsigned short*)(w + 68681728);     //  64 MB  [r][e]
    unsigned short* kb = (unsigned short*)(w + 135790592);    //  64 MB  [r][e]
    unsigned short* kt = (unsigned short*)(w + 202899456);    //  64 MB  [c][e][rl]
    unsigned short* vt = (unsigned short*)(w + 270008320);    //  64 MB  [c][d][rl]
    float*          G  = (float*)(w + 337117184);             //  64 MB  [c][d][e]
    unsigned short* Sp = (unsigned short*)(w + 404226048);    //  32 MB  [c][d][e]

    cvt_kernel<<<16384, 256, 0, stream>>>(x, xb, 33554432);
    cvt_kernel<<<128, 256, 0, stream>>>(Wq, wb, 262144);
    cvt_kernel<<<128, 256, 0, stream>>>(Wk, wb + 262144, 262144);
    cvt_kernel<<<128, 256, 0, stream>>>(Wv, wb + 524288, 262144);

    proj_kernel<<<1024, 256, 0, stream>>>(xb, wb, qb, kb, kt, vt);
    state_kernel<<<1024, 256, 0, stream>>>(kt, vt, G);
    scan_kernel<<<1024, 256, 0, stream>>>(G, m0, Sp);
    out_kernel<<<256, 512, 0, stream>>>(qb, kb, vt, Sp, (float*)d_out);
}